// Round 12
// baseline (624.390 us; speedup 1.0000x reference)
//
#include <hip/hip_runtime.h>

#define TT 256   // T
#define BB 512   // B
#define NG 256   // 4*H
#define KIN 128  // input width for both layers

typedef _Float16 half2v __attribute__((ext_vector_type(2)));
typedef _Float16 half4v __attribute__((ext_vector_type(4)));
typedef _Float16 half8v __attribute__((ext_vector_type(8)));
typedef float float4v __attribute__((ext_vector_type(4)));

__device__ __forceinline__ float sig_(float x){ return 1.f/(1.f+__expf(-x)); }
__device__ __forceinline__ float th_(float x){ return fmaf(2.f, 1.f/(1.f+__expf(-2.f*x)), -1.f); }

__device__ __forceinline__ half4v ld4h(const float* p){
  float4v v = *reinterpret_cast<const float4v*>(p);
  half4v h; h[0]=(_Float16)v[0]; h[1]=(_Float16)v[1]; h[2]=(_Float16)v[2]; h[3]=(_Float16)v[3];
  return h;
}

// ---- one-shot weight conversion fp32 -> fp16 (all row-major) ----
// halves offsets: wih_l0f 0, wih_l0r 32768, wih_l1f 65536,
//                 whh_l0f 98304, whh_l0r 114688, whh_l1f 131072
__global__ __launch_bounds__(256)
void conv_weights(const float* __restrict__ s0, const float* __restrict__ s1,
                  const float* __restrict__ s2, const float* __restrict__ s3,
                  const float* __restrict__ s4, const float* __restrict__ s5,
                  _Float16* __restrict__ dst)
{
  const int bid = blockIdx.x, tid = threadIdx.x;
  const float* src; int off, idx;
  if (bid < 128)      { src=s0; off=0;      idx=bid*256+tid; }
  else if (bid < 256) { src=s1; off=32768;  idx=(bid-128)*256+tid; }
  else if (bid < 384) { src=s2; off=65536;  idx=(bid-256)*256+tid; }
  else if (bid < 448) { src=s3; off=98304;  idx=(bid-384)*256+tid; }
  else if (bid < 512) { src=s4; off=114688; idx=(bid-448)*256+tid; }
  else                { src=s5; off=131072; idx=(bid-512)*256+tid; }
  dst[off+idx] = (_Float16)src[idx];
}

// C[m][n] = sum_k A[m][k]*W[n][k] + bias[n], written fp16.  (unchanged, ~20us)
template<typename AT>
__global__ __launch_bounds__(256)
void gemm_xg(const AT* __restrict__ A, const _Float16* __restrict__ W16,
             const float* __restrict__ bias, _Float16* __restrict__ Cout)
{
  __shared__ __align__(16) _Float16 aL[64][72];
  __shared__ __align__(16) _Float16 wL[256][72];
  const int tid  = threadIdx.x;
  const int wave = tid >> 6;
  const int lane = tid & 63;
  const int lr   = lane & 15;
  const int kg   = lane >> 4;
  const size_t m0 = (size_t)blockIdx.x * 64;

  float4v acc[4][4];
  #pragma unroll
  for (int a=0;a<4;a++)
    #pragma unroll
    for (int b=0;b<4;b++)
      acc[a][b] = float4v{0.f,0.f,0.f,0.f};

  for (int kc = 0; kc < KIN; kc += 64) {
    if constexpr (__is_same(AT, float)) {
      #pragma unroll
      for (int q=0;q<4;q++){
        int fi = tid + q*256;
        int r = fi >> 4, c4 = (fi & 15)*4;
        *reinterpret_cast<half4v*>(&aL[r][c4]) = ld4h(&A[(m0+(size_t)r)*KIN + kc + c4]);
      }
    } else {
      #pragma unroll
      for (int q=0;q<2;q++){
        int fi = tid + q*256;
        int r = fi >> 3, c8 = (fi & 7)*8;
        *reinterpret_cast<half8v*>(&aL[r][c8]) =
            *reinterpret_cast<const half8v*>(&A[(m0+(size_t)r)*KIN + kc + c8]);
      }
    }
    #pragma unroll
    for (int q=0;q<8;q++){
      int fi = tid + q*256;
      int n = fi >> 3, c8 = (fi & 7)*8;
      *reinterpret_cast<half8v*>(&wL[n][c8]) =
          *reinterpret_cast<const half8v*>(&W16[(size_t)n*KIN + kc + c8]);
    }
    __syncthreads();
    #pragma unroll
    for (int ks=0; ks<64; ks+=32){
      half8v af[4], bf[4];
      #pragma unroll
      for (int rt=0;rt<4;rt++)
        af[rt] = *reinterpret_cast<const half8v*>(&aL[rt*16+lr][ks + kg*8]);
      #pragma unroll
      for (int ct=0;ct<4;ct++)
        bf[ct] = *reinterpret_cast<const half8v*>(&wL[wave*64 + ct*16 + lr][ks + kg*8]);
      #pragma unroll
      for (int rt=0;rt<4;rt++)
        #pragma unroll
        for (int ct=0;ct<4;ct++)
          acc[rt][ct] = __builtin_amdgcn_mfma_f32_16x16x32_f16(af[rt], bf[ct], acc[rt][ct], 0,0,0);
    }
    __syncthreads();
  }
  #pragma unroll
  for (int ct=0;ct<4;ct++){
    const int col = wave*64 + ct*16 + lr;
    const float bv = bias[col];
    #pragma unroll
    for (int rt=0;rt<4;rt++){
      const size_t rbase = m0 + rt*16 + kg*4;
      #pragma unroll
      for (int i=0;i<4;i++)
        Cout[(rbase+(size_t)i)*NG + col] = (_Float16)(acc[rt][ct][i] + bv);
    }
  }
}

// ------------- r12: MFMA scan, lane-local gates, ONE barrier/step -------------
// Block = 16 batch rows, 256 thr / 4 waves. Wave w owns UNITS w*16..w*16+15
// across ALL FOUR gates (4 n-tiles, one per gate). MFMA C-layout (m89): lane
// (lr,kg) holds col=lr (unit w*16+lr), rows kg*4+i. So i,f,g,o for a given
// (row,unit) land in the SAME lane's 4 accs -> c/h update is lane-local, no
// acts exchange. h ping-pongs in swizzled LDS; ONE barrier per step.
// Weights: 32KB LDS, b128-XOR-swizzled, re-read 8 b128/lane/step (256cy/CU).
// xg C-init: 16 scalar b16 global loads/lane/step via 2-deep register ring.
template<int MODE>
__global__ __launch_bounds__(256, 1)
void lstm_scan_mm(const _Float16* __restrict__ xgPool,   // fwd 0, rev +BB*TT*NG
                  const _Float16* __restrict__ whhPool,  // fwd 0, rev +16384
                  int nF,
                  _Float16* __restrict__ x1out, float* __restrict__ hfin)
{
  const int tid = threadIdx.x;
  const int w   = tid >> 6;
  const int l   = tid & 63;
  const int lr  = l & 15;
  const int kg  = l >> 4;
  const bool rev = (int)blockIdx.x >= nF;
  const int bblk = rev ? ((int)blockIdx.x - nF) : (int)blockIdx.x;
  const int b0 = bblk * 16;
  const _Float16* xg  = xgPool  + (rev ? (size_t)BB*TT*NG : 0);
  const _Float16* whh = whhPool + (rev ? (size_t)16384 : 0);

  __shared__ __align__(16) _Float16 wlds[16384];     // 32KB, swizzled [col][128B]
  __shared__ __align__(16) _Float16 hlds[2][1024];   // 2x2KB ping-pong, swizzled

  // stage W: coalesced global, swizzled LDS (b128-safe: XOR bits 4..6)
  #pragma unroll
  for (int q=0;q<8;q++){
    const int u = q*256 + tid;
    const int col = u >> 3, k8 = u & 7;
    const int byte = (col*128 + k8*16) ^ ((col & 7) << 4);
    *reinterpret_cast<half8v*>((char*)wlds + byte) =
        *reinterpret_cast<const half8v*>(&whh[(size_t)u*8]);
  }
  ((unsigned*)hlds)[tid]     = 0u;     // zero page 0 (1024 halves)
  ((unsigned*)hlds)[tid+256] = 0u;
  float cc0=0.f, cc1=0.f, cc2=0.f, cc3=0.f;
  float hl0=0.f, hl1=0.f, hl2=0.f, hl3=0.f;
  __syncthreads();

  // invariant addresses
  const int swz  = (lr & 7) << 4;
  const int aof0 = (lr*128 +  0 + kg*16) ^ swz;        // A-frag kc=0
  const int aof1 = (lr*128 + 64 + kg*16) ^ swz;        // A-frag kc=1
  const int cA   = w*16 + lr;                          // unit col
  int bof[4][2];
  #pragma unroll
  for (int g=0; g<4; ++g){
    const int col = g*64 + cA;
    bof[g][0] = (col*128 +  0 + kg*16) ^ ((col & 7) << 4);
    bof[g][1] = (col*128 + 64 + kg*16) ^ ((col & 7) << 4);
  }
  int hw[4];
  #pragma unroll
  for (int i=0;i<4;i++){
    const int r = kg*4 + i;
    hw[i] = (r*128 + cA*2) ^ ((r & 7) << 4);
  }
  char* hb = (char*)hlds;
  char* wb = (char*)wlds;

  // xg ring: per step lane needs xg[b0+kg*4+i][t][g*64+cA], i,g in 0..3
  const int t0i = rev ? (TT-1) : 0;
  const ptrdiff_t dstep = rev ? -(ptrdiff_t)NG : (ptrdiff_t)NG;
  const _Float16* p0 = xg + ((size_t)(b0+kg*4+0)*TT + t0i)*NG + cA;
  const _Float16* p1 = xg + ((size_t)(b0+kg*4+1)*TT + t0i)*NG + cA;
  const _Float16* p2 = xg + ((size_t)(b0+kg*4+2)*TT + t0i)*NG + cA;
  const _Float16* p3 = xg + ((size_t)(b0+kg*4+3)*TT + t0i)*NG + cA;

  _Float16 rgA[16], rgB[16];
#define REFILL(S_) do {                                            \
    S_[0]=p0[0];    S_[1]=p1[0];    S_[2]=p2[0];    S_[3]=p3[0];   \
    S_[4]=p0[64];   S_[5]=p1[64];   S_[6]=p2[64];   S_[7]=p3[64];  \
    S_[8]=p0[128];  S_[9]=p1[128];  S_[10]=p2[128]; S_[11]=p3[128];\
    S_[12]=p0[192]; S_[13]=p1[192]; S_[14]=p2[192]; S_[15]=p3[192];\
    p0+=dstep; p1+=dstep; p2+=dstep; p3+=dstep;                    \
  } while(0)
  REFILL(rgA);
  REFILL(rgB);

  // x1 store bases (MODE 0)
  const int xoff = rev ? 64 : 0;
  _Float16* q0 = x1out ? x1out + ((size_t)(b0+kg*4+0)*TT)*128 + xoff + cA : nullptr;
  _Float16* q1 = x1out ? x1out + ((size_t)(b0+kg*4+1)*TT)*128 + xoff + cA : nullptr;
  _Float16* q2 = x1out ? x1out + ((size_t)(b0+kg*4+2)*TT)*128 + xoff + cA : nullptr;
  _Float16* q3 = x1out ? x1out + ((size_t)(b0+kg*4+3)*TT)*128 + xoff + cA : nullptr;

#define SCAN_STEP(tt_, S_) do {                                              \
    const int tt = (tt_);                                                    \
    const int t  = rev ? (TT-1-tt) : tt;                                     \
    const int p  = tt & 1;                                                   \
    /* C-init from ring (loaded 2 steps ago) */                              \
    float4v ac0, ac1, ac2, ac3;                                              \
    ac0[0]=(float)S_[0];  ac0[1]=(float)S_[1];                               \
    ac0[2]=(float)S_[2];  ac0[3]=(float)S_[3];                               \
    ac1[0]=(float)S_[4];  ac1[1]=(float)S_[5];                               \
    ac1[2]=(float)S_[6];  ac1[3]=(float)S_[7];                               \
    ac2[0]=(float)S_[8];  ac2[1]=(float)S_[9];                               \
    ac2[2]=(float)S_[10]; ac2[3]=(float)S_[11];                              \
    ac3[0]=(float)S_[12]; ac3[1]=(float)S_[13];                              \
    ac3[2]=(float)S_[14]; ac3[3]=(float)S_[15];                              \
    if (tt+2 < TT) REFILL(S_);                                               \
    /* A-frags from h page p */                                              \
    const half8v a0 = *reinterpret_cast<const half8v*>(hb + p*2048 + aof0);  \
    const half8v a1 = *reinterpret_cast<const half8v*>(hb + p*2048 + aof1);  \
    /* B-frags from swizzled LDS */                                          \
    const half8v b00 = *reinterpret_cast<const half8v*>(wb + bof[0][0]);     \
    const half8v b01 = *reinterpret_cast<const half8v*>(wb + bof[0][1]);     \
    const half8v b10 = *reinterpret_cast<const half8v*>(wb + bof[1][0]);     \
    const half8v b11 = *reinterpret_cast<const half8v*>(wb + bof[1][1]);     \
    const half8v b20 = *reinterpret_cast<const half8v*>(wb + bof[2][0]);     \
    const half8v b21 = *reinterpret_cast<const half8v*>(wb + bof[2][1]);     \
    const half8v b30 = *reinterpret_cast<const half8v*>(wb + bof[3][0]);     \
    const half8v b31 = *reinterpret_cast<const half8v*>(wb + bof[3][1]);     \
    ac0 = __builtin_amdgcn_mfma_f32_16x16x32_f16(a0, b00, ac0, 0,0,0);       \
    ac1 = __builtin_amdgcn_mfma_f32_16x16x32_f16(a0, b10, ac1, 0,0,0);       \
    ac2 = __builtin_amdgcn_mfma_f32_16x16x32_f16(a0, b20, ac2, 0,0,0);       \
    ac3 = __builtin_amdgcn_mfma_f32_16x16x32_f16(a0, b30, ac3, 0,0,0);       \
    ac0 = __builtin_amdgcn_mfma_f32_16x16x32_f16(a1, b01, ac0, 0,0,0);       \
    ac1 = __builtin_amdgcn_mfma_f32_16x16x32_f16(a1, b11, ac1, 0,0,0);       \
    ac2 = __builtin_amdgcn_mfma_f32_16x16x32_f16(a1, b21, ac2, 0,0,0);       \
    ac3 = __builtin_amdgcn_mfma_f32_16x16x32_f16(a1, b31, ac3, 0,0,0);       \
    /* lane-local gates: row kg*4+i, unit cA */                              \
    {                                                                        \
      const float i0=sig_(ac0[0]), f0=sig_(ac1[0]), g0=th_(ac2[0]), o0=sig_(ac3[0]); \
      const float i1=sig_(ac0[1]), f1=sig_(ac1[1]), g1=th_(ac2[1]), o1=sig_(ac3[1]); \
      const float i2=sig_(ac0[2]), f2=sig_(ac1[2]), g2=th_(ac2[2]), o2=sig_(ac3[2]); \
      const float i3=sig_(ac0[3]), f3=sig_(ac1[3]), g3=th_(ac2[3]), o3=sig_(ac3[3]); \
      cc0 = f0*cc0 + i0*g0;  cc1 = f1*cc1 + i1*g1;                           \
      cc2 = f2*cc2 + i2*g2;  cc3 = f3*cc3 + i3*g3;                           \
      const float h0v = o0*th_(cc0), h1v = o1*th_(cc1);                      \
      const float h2v = o2*th_(cc2), h3v = o3*th_(cc3);                      \
      char* hp = hb + (p^1)*2048;                                            \
      *reinterpret_cast<_Float16*>(hp + hw[0]) = (_Float16)h0v;              \
      *reinterpret_cast<_Float16*>(hp + hw[1]) = (_Float16)h1v;              \
      *reinterpret_cast<_Float16*>(hp + hw[2]) = (_Float16)h2v;              \
      *reinterpret_cast<_Float16*>(hp + hw[3]) = (_Float16)h3v;              \
      if constexpr (MODE==0){                                                \
        q0[(size_t)t*128] = (_Float16)h0v;                                   \
        q1[(size_t)t*128] = (_Float16)h1v;                                   \
        q2[(size_t)t*128] = (_Float16)h2v;                                   \
        q3[(size_t)t*128] = (_Float16)h3v;                                   \
      } else {                                                               \
        hl0=h0v; hl1=h1v; hl2=h2v; hl3=h3v;                                  \
      }                                                                      \
    }                                                                        \
    __syncthreads();                                                         \
  } while(0)

  for (int tb=0; tb<TT; tb+=2){
    SCAN_STEP(tb,   rgA);
    SCAN_STEP(tb+1, rgB);
  }
#undef SCAN_STEP
#undef REFILL

  if constexpr (MODE==1){
    hfin[(size_t)(b0+kg*4+0)*64 + cA] = hl0;
    hfin[(size_t)(b0+kg*4+1)*64 + cA] = hl1;
    hfin[(size_t)(b0+kg*4+2)*64 + cA] = hl2;
    hfin[(size_t)(b0+kg*4+3)*64 + cA] = hl3;
  }
}

// Layer-1 reverse collapses to ONE step from zero state on x1[:,T-1]; fuse with FC.
__global__ __launch_bounds__(256)
void final_fuse(const _Float16* __restrict__ x1, const float* __restrict__ w_ih,
                const float* __restrict__ bvec, const float* __restrict__ hfin,
                const float* __restrict__ fcw, const float* __restrict__ fcb,
                float* __restrict__ out)
{
  const int b = blockIdx.x, tid = threadIdx.x;
  __shared__ float xs[128];
  __shared__ float act[256];
  __shared__ float hall[128];
  if (tid < 128) xs[tid] = (float)x1[((size_t)b*TT + (TT-1))*128 + tid];
  __syncthreads();
  float a = bvec[tid];
  #pragma unroll
  for (int kk=0;kk<32;kk++){
    float4v wv = *reinterpret_cast<const float4v*>(&w_ih[(size_t)tid*128 + kk*4]);
    a += wv[0]*xs[kk*4] + wv[1]*xs[kk*4+1] + wv[2]*xs[kk*4+2] + wv[3]*xs[kk*4+3];
  }
  const int grp = tid>>6;
  act[tid] = (grp==2) ? th_(a) : sig_(a);
  __syncthreads();
  if (tid < 64) {
    float c = act[tid]*act[128+tid];        // c = i*g (c0 = 0)
    float h = act[192+tid]*th_(c);          // h = o*tanh(c)
    hall[64+tid] = h;
    hall[tid] = hfin[(size_t)b*64 + tid];
  }
  __syncthreads();
  if (tid < 3) {
    float acc2 = fcb[tid];
    for (int k=0;k<128;k++) acc2 += fcw[(size_t)tid*128 + k]*hall[k];
    out[(size_t)b*3 + tid] = acc2;
  }
}

extern "C" void kernel_launch(void* const* d_in, const int* in_sizes, int n_in,
                              void* d_out, int out_size, void* d_ws, size_t ws_size,
                              hipStream_t stream) {
  const float* x        = (const float*)d_in[0];
  const float* w_ih_l0f = (const float*)d_in[1];
  const float* w_hh_l0f = (const float*)d_in[2];
  const float* b_l0f    = (const float*)d_in[3];
  const float* w_ih_l0r = (const float*)d_in[4];
  const float* w_hh_l0r = (const float*)d_in[5];
  const float* b_l0r    = (const float*)d_in[6];
  const float* w_ih_l1f = (const float*)d_in[7];
  const float* w_hh_l1f = (const float*)d_in[8];
  const float* b_l1f    = (const float*)d_in[9];
  const float* w_ih_l1r = (const float*)d_in[10];
  const float* b_l1r    = (const float*)d_in[12];
  const float* fc_w     = (const float*)d_in[13];
  const float* fc_b     = (const float*)d_in[14];
  float* out = (float*)d_out;

  const size_t XG_BYTES = (size_t)BB*TT*NG*2;      // xgF then xgR ADJACENT
  const size_t X1_BYTES = (size_t)BB*TT*128*2;
  const size_t HF_BYTES = (size_t)BB*64*4;
  const size_t W16_BYTES = (size_t)147456*2;
  if (ws_size < 2*XG_BYTES + X1_BYTES + HF_BYTES + W16_BYTES) return;
  _Float16* xgF  = (_Float16*)d_ws;
  _Float16* xgR  = (_Float16*)((char*)d_ws + XG_BYTES);
  _Float16* x1   = (_Float16*)((char*)d_ws + 2*XG_BYTES);
  float*    hfin = (float*)   ((char*)d_ws + 2*XG_BYTES + X1_BYTES);
  _Float16* w16  = (_Float16*)((char*)d_ws + 2*XG_BYTES + X1_BYTES + HF_BYTES);
  _Float16* wih_l0f16 = w16;
  _Float16* wih_l0r16 = w16 + 32768;
  _Float16* wih_l1f16 = w16 + 65536;
  _Float16* whh_l0f16 = w16 + 98304;    // whh_l0r16 = +16384 (adjacent)
  _Float16* whh_l1f16 = w16 + 131072;

  const int MBLK = (BB*TT)/64;  // 2048

  conv_weights<<<576, 256, 0, stream>>>(w_ih_l0f, w_ih_l0r, w_ih_l1f,
                                        w_hh_l0f, w_hh_l0r, w_hh_l1f, w16);
  // layer 0: input GEMMs, then fused fwd+rev MFMA scan (64 blocks x 256 thr)
  gemm_xg<float><<<MBLK, 256, 0, stream>>>(x, wih_l0f16, b_l0f, xgF);
  gemm_xg<float><<<MBLK, 256, 0, stream>>>(x, wih_l0r16, b_l0r, xgR);
  lstm_scan_mm<0><<<64, 256, 0, stream>>>(xgF, whh_l0f16, 32, x1, nullptr);
  // layer 1 forward (only final h needed): 32 blocks
  gemm_xg<_Float16><<<MBLK, 256, 0, stream>>>(x1, wih_l1f16, b_l1f, xgF);
  lstm_scan_mm<1><<<32, 256, 0, stream>>>(xgF, whh_l1f16, 32, nullptr, hfin);
  // layer 1 reverse one-step + FC
  final_fuse<<<BB, 256, 0, stream>>>(x1, w_ih_l1r, b_l1r, hfin, fc_w, fc_b, out);
}

// Round 13
// 568.323 us; speedup vs baseline: 1.0987x; 1.0987x over previous
//
#include <hip/hip_runtime.h>

#define TT 256   // T
#define BB 512   // B
#define NG 256   // 4*H
#define KIN 128  // input width for both layers

typedef _Float16 half2v __attribute__((ext_vector_type(2)));
typedef _Float16 half4v __attribute__((ext_vector_type(4)));
typedef _Float16 half8v __attribute__((ext_vector_type(8)));
typedef float float4v __attribute__((ext_vector_type(4)));

__device__ __forceinline__ float sig_(float x){ return 1.f/(1.f+__expf(-x)); }
__device__ __forceinline__ float th_(float x){ return fmaf(2.f, 1.f/(1.f+__expf(-2.f*x)), -1.f); }

#define SV2(v,k) __builtin_shufflevector((v),(v), 2*(k), 2*(k)+1)

#if __has_builtin(__builtin_elementwise_fma)
__device__ __forceinline__ half2v pkfma_(half2v a, half2v b, half2v c){
  return __builtin_elementwise_fma(a, b, c);
}
#else
__device__ __forceinline__ half2v pkfma_(half2v a, half2v b, half2v c){
  return a*b + c;
}
#endif

__device__ __forceinline__ half4v ld4h(const float* p){
  float4v v = *reinterpret_cast<const float4v*>(p);
  half4v h; h[0]=(_Float16)v[0]; h[1]=(_Float16)v[1]; h[2]=(_Float16)v[2]; h[3]=(_Float16)v[3];
  return h;
}

// ---- one-shot weight conversion fp32 -> fp16 (row-major pool) ----
// halves offsets: wih_l0f 0, wih_l0r 32768, wih_l1f 65536,
//                 whh_l0f 98304, whh_l0r 114688, whh_l1f 131072
__global__ __launch_bounds__(256)
void conv_weights(const float* __restrict__ s0, const float* __restrict__ s1,
                  const float* __restrict__ s2, const float* __restrict__ s3,
                  const float* __restrict__ s4, const float* __restrict__ s5,
                  _Float16* __restrict__ dst)
{
  const int bid = blockIdx.x, tid = threadIdx.x;
  const float* src; int off, idx;
  if (bid < 128)      { src=s0; off=0;      idx=bid*256+tid; }
  else if (bid < 256) { src=s1; off=32768;  idx=(bid-128)*256+tid; }
  else if (bid < 384) { src=s2; off=65536;  idx=(bid-256)*256+tid; }
  else if (bid < 448) { src=s3; off=98304;  idx=(bid-384)*256+tid; }
  else if (bid < 512) { src=s4; off=114688; idx=(bid-448)*256+tid; }
  else                { src=s5; off=131072; idx=(bid-512)*256+tid; }
  dst[off+idx] = (_Float16)src[idx];
}

// C[m][n] = A[m][:]*W[n][:] + bias[n], written fp16 T-MAJOR: C[t][b][n],
// where m = b*TT + t. A: b-major fp32 (layer0) or t-major fp16 (layer1, ATM).
template<typename AT, bool ATM>
__global__ __launch_bounds__(256)
void gemm_xg(const AT* __restrict__ A, const _Float16* __restrict__ W16,
             const float* __restrict__ bias, _Float16* __restrict__ Cout)
{
  __shared__ __align__(16) _Float16 aL[64][72];
  __shared__ __align__(16) _Float16 wL[256][72];
  const int tid  = threadIdx.x;
  const int wave = tid >> 6;
  const int lane = tid & 63;
  const int lr   = lane & 15;
  const int kg   = lane >> 4;
  const int m0   = blockIdx.x * 64;     // tile spans one b, 64 consecutive t

  float4v acc[4][4];
  #pragma unroll
  for (int a=0;a<4;a++)
    #pragma unroll
    for (int b=0;b<4;b++)
      acc[a][b] = float4v{0.f,0.f,0.f,0.f};

  for (int kc = 0; kc < KIN; kc += 64) {
    if constexpr (!ATM) {
      #pragma unroll
      for (int q=0;q<4;q++){
        int fi = tid + q*256;
        int r = fi >> 4, c4 = (fi & 15)*4;
        *reinterpret_cast<half4v*>(&aL[r][c4]) = ld4h(&A[(size_t)(m0+r)*KIN + kc + c4]);
      }
    } else {
      #pragma unroll
      for (int q=0;q<2;q++){
        int fi = tid + q*256;
        int r = fi >> 3, c8 = (fi & 7)*8;
        const int m = m0 + r, tI = m & (TT-1), bI = m >> 8;
        *reinterpret_cast<half8v*>(&aL[r][c8]) =
            *reinterpret_cast<const half8v*>(&A[((size_t)tI*BB + bI)*KIN + kc + c8]);
      }
    }
    #pragma unroll
    for (int q=0;q<8;q++){
      int fi = tid + q*256;
      int n = fi >> 3, c8 = (fi & 7)*8;
      *reinterpret_cast<half8v*>(&wL[n][c8]) =
          *reinterpret_cast<const half8v*>(&W16[(size_t)n*KIN + kc + c8]);
    }
    __syncthreads();
    #pragma unroll
    for (int ks=0; ks<64; ks+=32){
      half8v af[4], bf[4];
      #pragma unroll
      for (int rt=0;rt<4;rt++)
        af[rt] = *reinterpret_cast<const half8v*>(&aL[rt*16+lr][ks + kg*8]);
      #pragma unroll
      for (int ct=0;ct<4;ct++)
        bf[ct] = *reinterpret_cast<const half8v*>(&wL[wave*64 + ct*16 + lr][ks + kg*8]);
      #pragma unroll
      for (int rt=0;rt<4;rt++)
        #pragma unroll
        for (int ct=0;ct<4;ct++)
          acc[rt][ct] = __builtin_amdgcn_mfma_f32_16x16x32_f16(af[rt], bf[ct], acc[rt][ct], 0,0,0);
    }
    __syncthreads();
  }
  // epilogue: t-major write C[t][b][col]
  #pragma unroll
  for (int ct=0;ct<4;ct++){
    const int col = wave*64 + ct*16 + lr;
    const float bv = bias[col];
    #pragma unroll
    for (int rt=0;rt<4;rt++){
      #pragma unroll
      for (int i=0;i<4;i++){
        const int m  = m0 + rt*16 + kg*4 + i;
        const int tI = m & (TT-1), bI = m >> 8;
        Cout[((size_t)tI*BB + bI)*NG + col] = (_Float16)(acc[rt][ct][i] + bv);
      }
    }
  }
}

// ---------- r13 scan: T-MAJOR xg (streaming HBM) + LDS weights + NB rows ----
// xg layout [t][b][256]: at step t all blocks read ONE contiguous slab ->
// streaming reads instead of r2-r12's 128KB-stride scatter (481 GB/s wall).
// Block: 256 thr / 4 waves, wave = gate, NB batch rows. Weights in 32KB LDS,
// unit layout [kk][row] (r10-proven conflict-free b128, imm offsets kk*4096).
// Phase1: lane = gate-col; 8 w-b128 + 8*NB broadcast h-b128 + 32*NB pk_fma
// (fp16 accum, r10-validated). acts f32 ping-pong; ONE barrier/step; update
// replicated in all 4 waves against per-wave-private h copies (r7 trick).
// xg ring: 4 named slots (static idx), refill distance 4 (~2400cy window).
template<int NB, int MODE>
__global__ __launch_bounds__(256, 2)
void lstm_scan_s(const _Float16* __restrict__ xgPool,   // t-major; fwd 0, rev +TT*BB*NG
                 const _Float16* __restrict__ whhPool,  // row-major; fwd 0, rev +16384
                 int nF,
                 _Float16* __restrict__ x1T,            // t-major [t][b][128]
                 float* __restrict__ hfin)
{
  const int tid = threadIdx.x;        // phase1: gate col
  const int w   = tid >> 6;           // wave = gate
  const int j   = tid & 63;
  const bool rev = (int)blockIdx.x >= nF;
  const int bblk = rev ? ((int)blockIdx.x - nF) : (int)blockIdx.x;
  const int r0 = bblk * NB;
  const _Float16* xg  = xgPool  + (rev ? (size_t)TT*BB*NG : 0);
  const _Float16* whh = whhPool + (rev ? (size_t)16384 : 0);

  __shared__ __align__(16) _Float16 wlds[16384];     // 32KB [kk][row] units
  __shared__ __align__(16) float    acts[2][NB][256];
  __shared__ __align__(16) _Float16 hsw[4][NB][64];  // per-wave private h

  // stage weights: thread u reads row-major unit u (row=u>>3, kk=u&7) ->
  // wlds unit (kk*256 + row)
  #pragma unroll
  for (int q=0;q<8;q++){
    const int u = q*256 + tid;
    *reinterpret_cast<half8v*>(&wlds[(((u & 7) << 8) + (u >> 3))*8]) =
        *reinterpret_cast<const half8v*>(&whh[(size_t)u*8]);
  }
  if (tid < NB*128) ((unsigned*)hsw)[tid] = 0u;      // zero all h copies
  float c0 = 0.f, c1 = 0.f, hl0 = 0.f, hl1 = 0.f;
  __syncthreads();

  const char* wb = (const char*)wlds;
  const int wrow = tid*16;                            // byte base, row=tid

  // xg pointer: front position, row r0, col tid; row r0+1 at +NG
  const ptrdiff_t dstep = (rev ? -(ptrdiff_t)1 : (ptrdiff_t)1) * (ptrdiff_t)(BB*NG);
  const _Float16* pA = xg + (size_t)(rev ? TT-1 : 0)*BB*NG + (size_t)r0*NG + tid;

  half2v s0v{0,0}, s1v{0,0}, s2v{0,0}, s3v{0,0};
#define LOADSLOT(S_) do {                                   \
    S_[0] = pA[0];                                          \
    if constexpr (NB==2) S_[1] = pA[NG];                    \
    pA += dstep;                                            \
  } while(0)
  LOADSLOT(s0v); LOADSLOT(s1v); LOADSLOT(s2v); LOADSLOT(s3v);

  const int xoff = rev ? 64 : 0;

#define STEP(tt_, S_) do {                                                    \
    const int tt  = (tt_);                                                    \
    const int t   = rev ? (TT-1-tt) : tt;                                     \
    const int par = tt & 1;                                                   \
    const float xr0 = (float)S_[0];                                           \
    float xr1 = 0.f;                                                          \
    if constexpr (NB==2) xr1 = (float)S_[1];                                  \
    if (tt+4 < TT) LOADSLOT(S_);                                              \
    half2v A0={0,0},A1={0,0},A2={0,0},A3={0,0};                               \
    half2v B0={0,0},B1={0,0},B2={0,0},B3={0,0};                               \
    _Pragma("unroll")                                                         \
    for (int kk=0;kk<8;kk++){                                                 \
      const half8v w8 = *reinterpret_cast<const half8v*>(wb + wrow + kk*4096);\
      const half8v h0 = *reinterpret_cast<const half8v*>(&hsw[w][0][kk*8]);   \
      A0 = pkfma_(SV2(w8,0), SV2(h0,0), A0);                                  \
      A1 = pkfma_(SV2(w8,1), SV2(h0,1), A1);                                  \
      A2 = pkfma_(SV2(w8,2), SV2(h0,2), A2);                                  \
      A3 = pkfma_(SV2(w8,3), SV2(h0,3), A3);                                  \
      if constexpr (NB==2){                                                   \
        const half8v h1 = *reinterpret_cast<const half8v*>(&hsw[w][1][kk*8]); \
        B0 = pkfma_(SV2(w8,0), SV2(h1,0), B0);                                \
        B1 = pkfma_(SV2(w8,1), SV2(h1,1), B1);                                \
        B2 = pkfma_(SV2(w8,2), SV2(h1,2), B2);                                \
        B3 = pkfma_(SV2(w8,3), SV2(h1,3), B3);                                \
      }                                                                       \
    }                                                                         \
    const half2v sa = (A0+A1)+(A2+A3);                                        \
    const float pre0 = xr0 + (float)sa[0] + (float)sa[1];                     \
    acts[par][0][tid] = (w==2) ? th_(pre0) : sig_(pre0);                      \
    if constexpr (NB==2){                                                     \
      const half2v sb = (B0+B1)+(B2+B3);                                      \
      const float pre1 = xr1 + (float)sb[0] + (float)sb[1];                   \
      acts[par][1][tid] = (w==2) ? th_(pre1) : sig_(pre1);                    \
    }                                                                         \
    __syncthreads();                                                          \
    {                                                                         \
      const float iv = acts[par][0][j];                                       \
      const float fv = acts[par][0][64+j];                                    \
      const float gv = acts[par][0][128+j];                                   \
      const float ov = acts[par][0][192+j];                                   \
      c0 = fv*c0 + iv*gv;                                                     \
      const float h0v = ov * th_(c0);                                         \
      hl0 = h0v;                                                              \
      hsw[w][0][j] = (_Float16)h0v;                                           \
      if constexpr (MODE==0)                                                  \
        if (w == 0)                                                           \
          x1T[((size_t)t*BB + r0)*128 + xoff + j] = (_Float16)h0v;            \
      if constexpr (NB==2){                                                   \
        const float iv1 = acts[par][1][j];                                    \
        const float fv1 = acts[par][1][64+j];                                 \
        const float gv1 = acts[par][1][128+j];                                \
        const float ov1 = acts[par][1][192+j];                                \
        c1 = fv1*c1 + iv1*gv1;                                                \
        const float h1v = ov1 * th_(c1);                                      \
        hl1 = h1v;                                                            \
        hsw[w][1][j] = (_Float16)h1v;                                         \
        if constexpr (MODE==0)                                                \
          if (w == 1)                                                         \
            x1T[((size_t)t*BB + r0+1)*128 + xoff + j] = (_Float16)h1v;        \
      }                                                                       \
    }                                                                         \
  } while(0)

  for (int tb=0; tb<TT; tb+=4){
    STEP(tb,   s0v);
    STEP(tb+1, s1v);
    STEP(tb+2, s2v);
    STEP(tb+3, s3v);
  }
#undef STEP
#undef LOADSLOT

  if constexpr (MODE==1){
    if (w == 0) hfin[(size_t)r0*64 + j] = hl0;
    if constexpr (NB==2)
      if (w == 1) hfin[(size_t)(r0+1)*64 + j] = hl1;
  }
}

// Layer-1 reverse = ONE step from zero state on x1[:,T-1] (t-major); fuse FC.
__global__ __launch_bounds__(256)
void final_fuse(const _Float16* __restrict__ x1T, const float* __restrict__ w_ih,
                const float* __restrict__ bvec, const float* __restrict__ hfin,
                const float* __restrict__ fcw, const float* __restrict__ fcb,
                float* __restrict__ out)
{
  const int b = blockIdx.x, tid = threadIdx.x;
  __shared__ float xs[128];
  __shared__ float act[256];
  __shared__ float hall[128];
  if (tid < 128) xs[tid] = (float)x1T[((size_t)(TT-1)*BB + b)*128 + tid];
  __syncthreads();
  float a = bvec[tid];
  #pragma unroll
  for (int kk=0;kk<32;kk++){
    float4v wv = *reinterpret_cast<const float4v*>(&w_ih[(size_t)tid*128 + kk*4]);
    a += wv[0]*xs[kk*4] + wv[1]*xs[kk*4+1] + wv[2]*xs[kk*4+2] + wv[3]*xs[kk*4+3];
  }
  const int grp = tid>>6;
  act[tid] = (grp==2) ? th_(a) : sig_(a);
  __syncthreads();
  if (tid < 64) {
    float c = act[tid]*act[128+tid];        // c = i*g (c0 = 0)
    float h = act[192+tid]*th_(c);          // h = o*tanh(c)
    hall[64+tid] = h;
    hall[tid] = hfin[(size_t)b*64 + tid];
  }
  __syncthreads();
  if (tid < 3) {
    float acc2 = fcb[tid];
    for (int k=0;k<128;k++) acc2 += fcw[(size_t)tid*128 + k]*hall[k];
    out[(size_t)b*3 + tid] = acc2;
  }
}

extern "C" void kernel_launch(void* const* d_in, const int* in_sizes, int n_in,
                              void* d_out, int out_size, void* d_ws, size_t ws_size,
                              hipStream_t stream) {
  const float* x        = (const float*)d_in[0];
  const float* w_ih_l0f = (const float*)d_in[1];
  const float* w_hh_l0f = (const float*)d_in[2];
  const float* b_l0f    = (const float*)d_in[3];
  const float* w_ih_l0r = (const float*)d_in[4];
  const float* w_hh_l0r = (const float*)d_in[5];
  const float* b_l0r    = (const float*)d_in[6];
  const float* w_ih_l1f = (const float*)d_in[7];
  const float* w_hh_l1f = (const float*)d_in[8];
  const float* b_l1f    = (const float*)d_in[9];
  const float* w_ih_l1r = (const float*)d_in[10];
  const float* b_l1r    = (const float*)d_in[12];
  const float* fc_w     = (const float*)d_in[13];
  const float* fc_b     = (const float*)d_in[14];
  float* out = (float*)d_out;

  const size_t XG_BYTES = (size_t)TT*BB*NG*2;      // t-major; xgF then xgR ADJACENT
  const size_t X1_BYTES = (size_t)TT*BB*128*2;     // t-major
  const size_t HF_BYTES = (size_t)BB*64*4;
  const size_t W16_BYTES = (size_t)147456*2;
  if (ws_size < 2*XG_BYTES + X1_BYTES + HF_BYTES + W16_BYTES) return;
  _Float16* xgF  = (_Float16*)d_ws;
  _Float16* x1T  = (_Float16*)((char*)d_ws + 2*XG_BYTES);
  float*    hfin = (float*)   ((char*)d_ws + 2*XG_BYTES + X1_BYTES);
  _Float16* w16  = (_Float16*)((char*)d_ws + 2*XG_BYTES + X1_BYTES + HF_BYTES);
  _Float16* xgR  = xgF + (size_t)TT*BB*NG;
  _Float16* wih_l0f16 = w16;
  _Float16* wih_l0r16 = w16 + 32768;
  _Float16* wih_l1f16 = w16 + 65536;
  _Float16* whh_l0f16 = w16 + 98304;    // whh_l0r16 = +16384 (adjacent)
  _Float16* whh_l1f16 = w16 + 131072;

  const int MBLK = (BB*TT)/64;  // 2048

  conv_weights<<<576, 256, 0, stream>>>(w_ih_l0f, w_ih_l0r, w_ih_l1f,
                                        w_hh_l0f, w_hh_l0r, w_hh_l1f, w16);
  // layer 0: input GEMMs write t-major; fused fwd+rev scan (512 blocks, NB=2)
  gemm_xg<float, false><<<MBLK, 256, 0, stream>>>(x, wih_l0f16, b_l0f, xgF);
  gemm_xg<float, false><<<MBLK, 256, 0, stream>>>(x, wih_l0r16, b_l0r, xgR);
  lstm_scan_s<2,0><<<512, 256, 0, stream>>>(xgF, whh_l0f16, 256, x1T, nullptr);
  // layer 1 forward (final h only): A is t-major x1T; scan NB=1, 512 blocks
  gemm_xg<_Float16, true><<<MBLK, 256, 0, stream>>>(x1T, wih_l1f16, b_l1f, xgF);
  lstm_scan_s<1,1><<<512, 256, 0, stream>>>(xgF, whh_l1f16, 512, nullptr, hfin);
  // layer 1 reverse one-step + FC
  final_fuse<<<BB, 256, 0, stream>>>(x1T, w_ih_l1r, b_l1r, hfin, fc_w, fc_b, out);
}

// Round 14
// 517.077 us; speedup vs baseline: 1.2075x; 1.0991x over previous
//
#include <hip/hip_runtime.h>

#define TT 256   // T
#define BB 512   // B
#define NG 256   // 4*H
#define KIN 128  // input width for both layers

typedef _Float16 half2v __attribute__((ext_vector_type(2)));
typedef _Float16 half4v __attribute__((ext_vector_type(4)));
typedef _Float16 half8v __attribute__((ext_vector_type(8)));
typedef float float4v __attribute__((ext_vector_type(4)));

__device__ __forceinline__ float sig_(float x){ return 1.f/(1.f+__expf(-x)); }
__device__ __forceinline__ float th_(float x){ return fmaf(2.f, 1.f/(1.f+__expf(-2.f*x)), -1.f); }

#if __has_builtin(__builtin_amdgcn_fdot2)
__device__ __forceinline__ float fdot2_(half2v a, half2v b, float c){
  return __builtin_amdgcn_fdot2(a, b, c, false);
}
#else
__device__ __forceinline__ float fdot2_(half2v a, half2v b, float c){
  return c + (float)a[0]*(float)b[0] + (float)a[1]*(float)b[1];
}
#endif

#define SV2(v,k) __builtin_shufflevector((v),(v), 2*(k), 2*(k)+1)

__device__ __forceinline__ half4v ld4h(const float* p){
  float4v v = *reinterpret_cast<const float4v*>(p);
  half4v h; h[0]=(_Float16)v[0]; h[1]=(_Float16)v[1]; h[2]=(_Float16)v[2]; h[3]=(_Float16)v[3];
  return h;
}

// ---- one-shot weight conversion fp32 -> fp16 into ws pool (row-major) ----
// halves offsets: wih_l0f 0, wih_l0r 32768, wih_l1f 65536,
//                 whh_l0f 98304, whh_l0r 114688, whh_l1f 131072
__global__ __launch_bounds__(256)
void conv_weights(const float* __restrict__ s0, const float* __restrict__ s1,
                  const float* __restrict__ s2, const float* __restrict__ s3,
                  const float* __restrict__ s4, const float* __restrict__ s5,
                  _Float16* __restrict__ dst)
{
  const int bid = blockIdx.x, tid = threadIdx.x;
  const float* src; int off, idx;
  if (bid < 128)      { src=s0; off=0;      idx=bid*256+tid; }
  else if (bid < 256) { src=s1; off=32768;  idx=(bid-128)*256+tid; }
  else if (bid < 384) { src=s2; off=65536;  idx=(bid-256)*256+tid; }
  else if (bid < 448) { src=s3; off=98304;  idx=(bid-384)*256+tid; }
  else if (bid < 512) { src=s4; off=114688; idx=(bid-448)*256+tid; }
  else                { src=s5; off=131072; idx=(bid-512)*256+tid; }
  dst[off+idx] = (_Float16)src[idx];
}

// C[m][n] = sum_k A[m][k]*W[n][k] + bias[n], written fp16 (b-major, r8 layout).
template<typename AT>
__global__ __launch_bounds__(256)
void gemm_xg(const AT* __restrict__ A, const _Float16* __restrict__ W16,
             const float* __restrict__ bias, _Float16* __restrict__ Cout)
{
  __shared__ __align__(16) _Float16 aL[64][72];
  __shared__ __align__(16) _Float16 wL[256][72];
  const int tid  = threadIdx.x;
  const int wave = tid >> 6;
  const int lane = tid & 63;
  const int lr   = lane & 15;
  const int kg   = lane >> 4;
  const size_t m0 = (size_t)blockIdx.x * 64;

  float4v acc[4][4];
  #pragma unroll
  for (int a=0;a<4;a++)
    #pragma unroll
    for (int b=0;b<4;b++)
      acc[a][b] = float4v{0.f,0.f,0.f,0.f};

  for (int kc = 0; kc < KIN; kc += 64) {
    if constexpr (__is_same(AT, float)) {
      #pragma unroll
      for (int q=0;q<4;q++){
        int fi = tid + q*256;
        int r = fi >> 4, c4 = (fi & 15)*4;
        *reinterpret_cast<half4v*>(&aL[r][c4]) = ld4h(&A[(m0+(size_t)r)*KIN + kc + c4]);
      }
    } else {
      #pragma unroll
      for (int q=0;q<2;q++){
        int fi = tid + q*256;
        int r = fi >> 3, c8 = (fi & 7)*8;
        *reinterpret_cast<half8v*>(&aL[r][c8]) =
            *reinterpret_cast<const half8v*>(&A[(m0+(size_t)r)*KIN + kc + c8]);
      }
    }
    #pragma unroll
    for (int q=0;q<8;q++){
      int fi = tid + q*256;
      int n = fi >> 3, c8 = (fi & 7)*8;
      *reinterpret_cast<half8v*>(&wL[n][c8]) =
          *reinterpret_cast<const half8v*>(&W16[(size_t)n*KIN + kc + c8]);
    }
    __syncthreads();
    #pragma unroll
    for (int ks=0; ks<64; ks+=32){
      half8v af[4], bf[4];
      #pragma unroll
      for (int rt=0;rt<4;rt++)
        af[rt] = *reinterpret_cast<const half8v*>(&aL[rt*16+lr][ks + kg*8]);
      #pragma unroll
      for (int ct=0;ct<4;ct++)
        bf[ct] = *reinterpret_cast<const half8v*>(&wL[wave*64 + ct*16 + lr][ks + kg*8]);
      #pragma unroll
      for (int rt=0;rt<4;rt++)
        #pragma unroll
        for (int ct=0;ct<4;ct++)
          acc[rt][ct] = __builtin_amdgcn_mfma_f32_16x16x32_f16(af[rt], bf[ct], acc[rt][ct], 0,0,0);
    }
    __syncthreads();
  }
  #pragma unroll
  for (int ct=0;ct<4;ct++){
    const int col = wave*64 + ct*16 + lr;
    const float bv = bias[col];
    #pragma unroll
    for (int rt=0;rt<4;rt++){
      const size_t rbase = m0 + rt*16 + kg*4;
      #pragma unroll
      for (int i=0;i<4;i++)
        Cout[(rbase+(size_t)i)*NG + col] = (_Float16)(acc[rt][ct][i] + bv);
    }
  }
}

// LSTM scan r14 = r8 structure (best known: 1 row/block, 4 waves, wave=gate,
// ONE barrier/step) with weights moved from scratch/L2 into LDS unit layout
// [kk][row] (r13-counter-validated conflict-free b128: at fixed kk, 64 lanes
// read 1KB contiguous; imm offsets kk*4096). r7/r8's VGPR=36 proved the
// "weight registers" lived in scratch -> per-step L2-latency reloads; LDS
// reads are ~30cy and burn no L2 BW.
template<int MODE>
__global__ __launch_bounds__(256, 4)
void lstm_scan_g4(const _Float16* __restrict__ xgPool,   // fwd at 0, rev at +BB*TT*NG
                  const _Float16* __restrict__ whhPool,  // fwd at 0, rev at +16384
                  int nF,
                  _Float16* __restrict__ x1out, float* __restrict__ hfin)
{
  const int tid = threadIdx.x;
  const int w   = tid >> 6;        // wave id = gate id (0:i 1:f 2:g 3:o)
  const int j   = tid & 63;        // hidden unit / gate row within gate
  const bool rev = (int)blockIdx.x >= nF;
  const int b = rev ? ((int)blockIdx.x - nF) : (int)blockIdx.x;
  const _Float16* xg  = xgPool  + (rev ? (size_t)BB*TT*NG : 0);
  const _Float16* whh = whhPool + (rev ? (size_t)16384 : 0);

  __shared__ __align__(16) _Float16 wlds[16384];    // 32KB [kk][row] half8 units
  __shared__ __align__(16) float acts[2][256];      // ping-pong by t parity
  __shared__ __align__(16) _Float16 hs4[4][64];     // per-wave private h copy

  // stage weights: thread reads row-major unit u (coalesced), writes [kk][row]
  #pragma unroll
  for (int q=0;q<8;q++){
    const int u = q*256 + tid;
    *reinterpret_cast<half8v*>(&wlds[(((u & 7) << 8) + (u >> 3))*8]) =
        *reinterpret_cast<const half8v*>(&whh[(size_t)u*8]);
  }
  hs4[w][j] = (_Float16)0.f;     // same-wave write; ordered vs our own reads
  float c = 0.f, h_last = 0.f;
  __syncthreads();

  const char* wb = (const char*)wlds;
  const int wbase = tid*16;      // byte base: row = tid (= w*64+j), kk via +kk*4096

  const _Float16* xgb = xg + (size_t)b*TT*NG + tid;
  _Float16 ring[8];              // static indices after unroll-8
  #pragma unroll
  for (int u=0;u<8;u++)
    ring[u] = xgb[(size_t)(rev ? (TT-1-u) : u) * NG];

  for (int tb=0; tb<TT; tb+=8){
    #pragma unroll
    for (int u=0;u<8;u++){
      const int tt = tb + u;
      const int t  = rev ? (TT-1-tt) : tt;

      const float xp = (float)ring[u];          // loaded 8 steps ago
      const int tf = tt + 8;
      if (tf < TT)
        ring[u] = xgb[(size_t)(rev ? (TT-1-tf) : tf) * NG];

      // dot: w_hh[row tid] . h   (2 fp32 chains); weights from LDS, h broadcast
      float a=0.f, a2=0.f;
      #pragma unroll
      for (int q=0;q<8;q++){
        const half8v w8 = *reinterpret_cast<const half8v*>(wb + wbase + q*4096);
        const half8v h8 = *reinterpret_cast<const half8v*>(&hs4[w][q*8]);
        a  = fdot2_(SV2(w8,0), SV2(h8,0), a);
        a2 = fdot2_(SV2(w8,1), SV2(h8,1), a2);
        a  = fdot2_(SV2(w8,2), SV2(h8,2), a);
        a2 = fdot2_(SV2(w8,3), SV2(h8,3), a2);
      }
      const float pre = xp + (a + a2);
      acts[tt&1][tid] = (w==2) ? th_(pre) : sig_(pre);   // wave-uniform branch
      __syncthreads();

      const float iv = acts[tt&1][j];
      const float fv = acts[tt&1][64+j];
      const float gv = acts[tt&1][128+j];
      const float ov = acts[tt&1][192+j];
      c = fv*c + iv*gv;                        // replicated identically in all 4 waves
      const float h = ov * th_(c);
      h_last = h;
      hs4[w][j] = (_Float16)h;                 // private copy; no barrier needed
      if constexpr (MODE==0)
        if (w == 0)
          x1out[((size_t)b*TT + t)*128 + (rev ? 64 : 0) + j] = (_Float16)h;
    }
  }
  if constexpr (MODE==1)
    if (w == 0)
      hfin[(size_t)b*64 + j] = h_last;
}

// Layer-1 reverse collapses to ONE step from zero state on x1[:,T-1]; fuse with FC.
__global__ __launch_bounds__(256)
void final_fuse(const _Float16* __restrict__ x1, const float* __restrict__ w_ih,
                const float* __restrict__ bvec, const float* __restrict__ hfin,
                const float* __restrict__ fcw, const float* __restrict__ fcb,
                float* __restrict__ out)
{
  const int b = blockIdx.x, tid = threadIdx.x;
  __shared__ float xs[128];
  __shared__ float act[256];
  __shared__ float hall[128];
  if (tid < 128) xs[tid] = (float)x1[((size_t)b*TT + (TT-1))*128 + tid];
  __syncthreads();
  float a = bvec[tid];
  #pragma unroll
  for (int kk=0;kk<32;kk++){
    float4v wv = *reinterpret_cast<const float4v*>(&w_ih[(size_t)tid*128 + kk*4]);
    a += wv[0]*xs[kk*4] + wv[1]*xs[kk*4+1] + wv[2]*xs[kk*4+2] + wv[3]*xs[kk*4+3];
  }
  const int grp = tid>>6;
  act[tid] = (grp==2) ? th_(a) : sig_(a);
  __syncthreads();
  if (tid < 64) {
    float c = act[tid]*act[128+tid];        // c = i*g (c0 = 0)
    float h = act[192+tid]*th_(c);          // h = o*tanh(c)
    hall[64+tid] = h;
    hall[tid] = hfin[(size_t)b*64 + tid];
  }
  __syncthreads();
  if (tid < 3) {
    float acc2 = fcb[tid];
    for (int k=0;k<128;k++) acc2 += fcw[(size_t)tid*128 + k]*hall[k];
    out[(size_t)b*3 + tid] = acc2;
  }
}

extern "C" void kernel_launch(void* const* d_in, const int* in_sizes, int n_in,
                              void* d_out, int out_size, void* d_ws, size_t ws_size,
                              hipStream_t stream) {
  const float* x        = (const float*)d_in[0];
  const float* w_ih_l0f = (const float*)d_in[1];
  const float* w_hh_l0f = (const float*)d_in[2];
  const float* b_l0f    = (const float*)d_in[3];
  const float* w_ih_l0r = (const float*)d_in[4];
  const float* w_hh_l0r = (const float*)d_in[5];
  const float* b_l0r    = (const float*)d_in[6];
  const float* w_ih_l1f = (const float*)d_in[7];
  const float* w_hh_l1f = (const float*)d_in[8];
  const float* b_l1f    = (const float*)d_in[9];
  const float* w_ih_l1r = (const float*)d_in[10];
  const float* b_l1r    = (const float*)d_in[12];
  const float* fc_w     = (const float*)d_in[13];
  const float* fc_b     = (const float*)d_in[14];
  float* out = (float*)d_out;

  // workspace layout (bytes)
  const size_t XG_BYTES = (size_t)BB*TT*NG*2;      // xgF then xgR ADJACENT
  const size_t X1_BYTES = (size_t)BB*TT*128*2;
  const size_t HF_BYTES = (size_t)BB*64*4;
  const size_t W16_BYTES = (size_t)147456*2;
  if (ws_size < 2*XG_BYTES + X1_BYTES + HF_BYTES + W16_BYTES) return;
  _Float16* xgF  = (_Float16*)d_ws;
  _Float16* xgR  = (_Float16*)((char*)d_ws + XG_BYTES);   // = xgF + BB*TT*NG halves
  _Float16* x1   = (_Float16*)((char*)d_ws + 2*XG_BYTES);
  float*    hfin = (float*)   ((char*)d_ws + 2*XG_BYTES + X1_BYTES);
  _Float16* w16  = (_Float16*)((char*)d_ws + 2*XG_BYTES + X1_BYTES + HF_BYTES);
  _Float16* wih_l0f16 = w16;
  _Float16* wih_l0r16 = w16 + 32768;
  _Float16* wih_l1f16 = w16 + 65536;
  _Float16* whh_l0f16 = w16 + 98304;    // whh_l0r16 = +16384 halves (adjacent)
  _Float16* whh_l1f16 = w16 + 131072;

  const int MBLK = (BB*TT)/64;  // 2048

  conv_weights<<<576, 256, 0, stream>>>(w_ih_l0f, w_ih_l0r, w_ih_l1f,
                                        w_hh_l0f, w_hh_l0r, w_hh_l1f, w16);
  // layer 0: both input GEMMs, then fused fwd+rev scan (1024 4-wave blocks)
  gemm_xg<float><<<MBLK, 256, 0, stream>>>(x, wih_l0f16, b_l0f, xgF);
  gemm_xg<float><<<MBLK, 256, 0, stream>>>(x, wih_l0r16, b_l0r, xgR);
  lstm_scan_g4<0><<<1024, 256, 0, stream>>>(xgF, whh_l0f16, 512, x1, nullptr);
  // layer 1 forward (only final h needed)
  gemm_xg<_Float16><<<MBLK, 256, 0, stream>>>(x1, wih_l1f16, b_l1f, xgF);
  lstm_scan_g4<1><<<512, 256, 0, stream>>>(xgF, whh_l1f16, 512, nullptr, hfin);
  // layer 1 reverse one-step + FC
  final_fuse<<<BB, 256, 0, stream>>>(x1, w_ih_l1r, b_l1r, hfin, fc_w, fc_b, out);
}